// Round 3
// baseline (643.740 us; speedup 1.0000x reference)
//
#include <hip/hip_runtime.h>
#include <cfloat>

// Problem constants (B=8, S=2048, D=256, K=8192)
#define N_TOK 16384
#define DIM 256
#define KCB 8192
#define BETA_C 0.25f
#define SLAB 4096
#define NSLAB 4
#define NSTRIPE 64   // 8192 / 128 cols per block

typedef __attribute__((ext_vector_type(8))) short short8;   // 8 bf16 (4 VGPRs)
typedef __attribute__((ext_vector_type(4))) float f32x4;    // MFMA acc
typedef unsigned short ushort_t;

// Swizzled byte offset within a [128 rows][64 bf16] LDS tile (128 B rows).
// XOR of byte-bits 4-6 with row&7 kills the 16-way bank conflict on frag reads.
__device__ __forceinline__ int swz(int row, int byte_in_row) {
    return row * 128 + (byte_in_row ^ ((row & 7) << 4));
}

__device__ __forceinline__ void async_copy16(const void* g, void* l) {
    __builtin_amdgcn_global_load_lds(
        (const __attribute__((address_space(1))) unsigned int*)g,
        (__attribute__((address_space(3))) unsigned int*)l, 16, 0, 0);
}

// ---------------- prep: f32 -> bf16 hi/lo planes (+ norms for emb) ----------------
// One wave per row; lane handles one float4 (D=256 = 64 lanes x 4).
template <int WITH_NORM>
__global__ void __launch_bounds__(256)
prep_kernel(const float* __restrict__ src, ushort_t* __restrict__ ph,
            ushort_t* __restrict__ pl, float* __restrict__ norm, int nrows) {
    const int w = threadIdx.x >> 6, lane = threadIdx.x & 63;
    const int r = blockIdx.x * 4 + w;
    if (r >= nrows) return;
    const float4 v = *reinterpret_cast<const float4*>(src + (size_t)r * DIM + lane * 4);
    const float vv[4] = {v.x, v.y, v.z, v.w};
    unsigned hw[2], lw[2];
    float s = 0.f;
#pragma unroll
    for (int j = 0; j < 2; ++j) {
        unsigned h0, h1, l0, l1;
        {
            const float f = vv[2 * j];
            s += f * f;
            const unsigned u = __float_as_uint(f);
            h0 = u >> 16;
            const float hf = __uint_as_float(u & 0xFFFF0000u);
            l0 = __float_as_uint(f - hf) >> 16;
        }
        {
            const float f = vv[2 * j + 1];
            s += f * f;
            const unsigned u = __float_as_uint(f);
            h1 = u >> 16;
            const float hf = __uint_as_float(u & 0xFFFF0000u);
            l1 = __float_as_uint(f - hf) >> 16;
        }
        hw[j] = h0 | (h1 << 16);
        lw[j] = l0 | (l1 << 16);
    }
    *reinterpret_cast<uint2*>(ph + (size_t)r * DIM + lane * 4) = make_uint2(hw[0], hw[1]);
    *reinterpret_cast<uint2*>(pl + (size_t)r * DIM + lane * 4) = make_uint2(lw[0], lw[1]);
    if (WITH_NORM) {
#pragma unroll
        for (int o = 32; o > 0; o >>= 1) s += __shfl_down(s, o, 64);
        if (lane == 0) norm[r] = s;
    }
}

// ---------------- MFMA distance GEMM + per-stripe top-2 ----------------
// Block: 128 slab rows x 128 codes (stripe). Sweeps virtual K=768:
// dot = xh.eh + xl.eh + xh.el.  dist = ||e||^2 - 2*dot (row-const ||x||^2 dropped).
__global__ void __launch_bounds__(256, 2)
dist_kernel(const ushort_t* __restrict__ xh, const ushort_t* __restrict__ xl,
            const ushort_t* __restrict__ eh, const ushort_t* __restrict__ el,
            const float* __restrict__ enorm, uint4* __restrict__ mg) {
    __shared__ char sb[65536];       // [0,16K) A-tile, [16K,32K) B-tile; epilogue: sc[64K)
    __shared__ float enormS[128];

    const int tid = threadIdx.x;
    const int lane = tid & 63;
    const int w = tid >> 6;
    const int wy = w >> 1, wx = w & 1;
    const int l15 = lane & 15, l4 = lane >> 4;
    const int row0 = blockIdx.x * 128;     // slab-local token row
    const int col0 = blockIdx.y * 128;     // global code col
    const int rr = lane >> 3;              // sub-row within a 1KB staging call
    const int egr = (lane & 7) ^ rr;       // pre-swizzled source granule

    if (tid < 128) enormS[tid] = enorm[col0 + tid];

    f32x4 acc[4][4];
#pragma unroll
    for (int m = 0; m < 4; ++m)
#pragma unroll
        for (int n = 0; n < 4; ++n) {
            f32x4 z = {0.f, 0.f, 0.f, 0.f};
            acc[m][n] = z;
        }

    const ushort_t* Ap[3] = {xh, xl, xh};
    const ushort_t* Bp[3] = {eh, eh, el};

    for (int p = 0; p < 3; ++p) {
        const ushort_t* __restrict__ A = Ap[p];
        const ushort_t* __restrict__ B = Bp[p];
        for (int dc = 0; dc < 4; ++dc) {
            __syncthreads();   // previous iter's readers done; barrier drains vmcnt
#pragma unroll
            for (int i = 0; i < 4; ++i) {
                const int rA = row0 + (w * 4 + i) * 8 + rr;
                async_copy16(A + (size_t)rA * DIM + dc * 64 + egr * 8,
                             sb + (w * 4 + i) * 1024);
            }
#pragma unroll
            for (int i = 0; i < 4; ++i) {
                const int rB = col0 + (w * 4 + i) * 8 + rr;
                async_copy16(B + (size_t)rB * DIM + dc * 64 + egr * 8,
                             sb + 16384 + (w * 4 + i) * 1024);
            }
            __syncthreads();   // compiler drains vmcnt(0) before this barrier
#pragma unroll
            for (int ks = 0; ks < 2; ++ks) {
                short8 af[4], bf[4];
#pragma unroll
                for (int m = 0; m < 4; ++m) {
                    const int r = wy * 64 + m * 16 + l15;
                    af[m] = *reinterpret_cast<const short8*>(sb + swz(r, ks * 64 + l4 * 16));
                }
#pragma unroll
                for (int n = 0; n < 4; ++n) {
                    const int r = wx * 64 + n * 16 + l15;
                    bf[n] = *reinterpret_cast<const short8*>(sb + 16384 + swz(r, ks * 64 + l4 * 16));
                }
#pragma unroll
                for (int m = 0; m < 4; ++m)
#pragma unroll
                    for (int n = 0; n < 4; ++n)
                        acc[m][n] = __builtin_amdgcn_mfma_f32_16x16x32_bf16(af[m], bf[n], acc[m][n], 0, 0, 0);
            }
        }
    }

    // epilogue: dist = enorm - 2*dot; per-row-slot top-2 over this block's 128 cols
    float tv1[16], tv2[16];
    int ti1[16], ti2[16];
#pragma unroll
    for (int s = 0; s < 16; ++s) { tv1[s] = FLT_MAX; tv2[s] = FLT_MAX; ti1[s] = 0; ti2[s] = 0; }
#pragma unroll
    for (int n = 0; n < 4; ++n) {
        const int cl = wx * 64 + n * 16 + l15;
        const int kg = col0 + cl;
        const float en = enormS[cl];
#pragma unroll
        for (int m = 0; m < 4; ++m)
#pragma unroll
            for (int j = 0; j < 4; ++j) {
                const float v = fmaf(-2.f, acc[m][n][j], en);
                const int s = m * 4 + j;
                if (v < tv1[s]) {
                    tv2[s] = tv1[s]; ti2[s] = ti1[s];
                    tv1[s] = v; ti1[s] = kg;
                } else if (v < tv2[s]) {
                    tv2[s] = v; ti2[s] = kg;
                }
            }
    }

    // block-level merge (32 contributors per row) via LDS, then write stripe entry
    __syncthreads();
    uint4* sc = reinterpret_cast<uint4*>(sb);   // [256 threads][16 slots]
#pragma unroll
    for (int s = 0; s < 16; ++s)
        sc[tid * 16 + s] = make_uint4(__float_as_uint(tv1[s]), (unsigned)ti1[s],
                                      __float_as_uint(tv2[s]), (unsigned)ti2[s]);
    __syncthreads();
    if (tid < 128) {
        const int r = tid;
        const int wy2 = r >> 6, lr = r & 63;
        const int m = lr >> 4, g = (lr & 15) >> 2, j = lr & 3, s = m * 4 + j;
        float v1 = FLT_MAX, v2 = FLT_MAX;
        int i1 = 0, i2 = 0;
        for (int wx2 = 0; wx2 < 2; ++wx2)
            for (int c = 0; c < 16; ++c) {
                const uint4 q = sc[(size_t)(((wy2 * 2 + wx2) * 64 + g * 16 + c) * 16 + s)];
                const float a1 = __uint_as_float(q.x), a2 = __uint_as_float(q.z);
                if (a1 < v1) {
                    if (a2 < v1) { v1 = a1; i1 = (int)q.y; v2 = a2; i2 = (int)q.w; }
                    else { v2 = v1; i2 = i1; v1 = a1; i1 = (int)q.y; }
                } else if (a1 < v2) { v2 = a1; i2 = (int)q.y; }
            }
        mg[(size_t)(row0 + r) * NSTRIPE + blockIdx.y] =
            make_uint4(__float_as_uint(v1), (unsigned)i1, __float_as_uint(v2), (unsigned)i2);
    }
}

// ---------------- merge stripes + exact f32 rescore ----------------
// One wave per row: 64 stripe entries -> measured global top-2 -> exact rescore.
__global__ void __launch_bounds__(256)
merge_fixup_kernel(const float* __restrict__ x, const float* __restrict__ emb,
                   const uint4* __restrict__ mg, int* __restrict__ idx_out,
                   float* __restrict__ minq, int row_base) {
    const int w = threadIdx.x >> 6, lane = threadIdx.x & 63;
    const int nl = blockIdx.x * 4 + w;    // slab-local row
    const int n = row_base + nl;          // global row
    const uint4 q = mg[(size_t)nl * NSTRIPE + lane];
    float v1 = __uint_as_float(q.x), v2 = __uint_as_float(q.z);
    int i1 = (int)q.y, i2 = (int)q.w;
#pragma unroll
    for (int o = 1; o < 64; o <<= 1) {
        const float b1 = __shfl_xor(v1, o, 64), b2 = __shfl_xor(v2, o, 64);
        const int j1 = __shfl_xor(i1, o, 64), j2 = __shfl_xor(i2, o, 64);
        const bool bf_ = (b1 < v1) || (b1 == v1 && j1 < i1);
        const float nv1 = bf_ ? b1 : v1; const int ni1 = bf_ ? j1 : i1;
        const float c = bf_ ? v1 : b1;   const int ci = bf_ ? i1 : j1;  // loser of firsts
        const float d = bf_ ? b2 : v2;   const int di = bf_ ? j2 : i2;  // winner's second
        const bool ds_ = (d < c) || (d == c && di < ci);
        v1 = nv1; i1 = ni1;
        v2 = ds_ ? d : c; i2 = ds_ ? di : ci;
    }
    // exact rescore of the two candidates
    const float4 xv = *reinterpret_cast<const float4*>(x + (size_t)n * DIM + lane * 4);
    float dsum[2];
    const int cand[2] = {i1, i2};
#pragma unroll
    for (int c = 0; c < 2; ++c) {
        const float4 ev = *reinterpret_cast<const float4*>(emb + (size_t)cand[c] * DIM + lane * 4);
        const float dx = xv.x - ev.x, dy = xv.y - ev.y, dz = xv.z - ev.z, dw = xv.w - ev.w;
        float s = dx * dx + dy * dy + dz * dz + dw * dw;
#pragma unroll
        for (int o = 32; o > 0; o >>= 1) s += __shfl_xor(s, o, 64);
        dsum[c] = s;
    }
    const bool take2 = (dsum[1] < dsum[0]) || (dsum[1] == dsum[0] && cand[1] < cand[0]);
    if (lane == 0) {
        idx_out[n] = take2 ? cand[1] : cand[0];
        minq[n] = take2 ? dsum[1] : dsum[0];
    }
}

// ---------------- MLP layers (unchanged, proven) ----------------
#define BR 64
#define BKT 64
#define DC 64
#define LSTR 66
template <int MODE>
__global__ void __launch_bounds__(256)
mlp_kernel(const float* __restrict__ src, const float* __restrict__ emb,
           const int* __restrict__ idx, const float* __restrict__ W,
           const float* __restrict__ bias, float* __restrict__ out) {
    __shared__ float rs[BR][LSTR];
    __shared__ float wsl[BKT][LSTR];
    __shared__ int idxs[BR];

    const int tid = threadIdx.x;
    const int ty = tid >> 4, tx = tid & 15;
    const int row0 = blockIdx.x * BR;
    const int e0 = blockIdx.y * BKT;

    if (tid < BR) idxs[tid] = idx[row0 + tid];

    float acc[4][4];
#pragma unroll
    for (int a = 0; a < 4; ++a)
#pragma unroll
        for (int b = 0; b < 4; ++b) acc[a][b] = 0.f;

    for (int dc = 0; dc < DIM / DC; ++dc) {
        __syncthreads();
#pragma unroll
        for (int i = 0; i < 4; ++i) {
            const int f = tid + 256 * i;
            const int r = f >> 4;
            const int c4 = f & 15;
            float4 sv = *reinterpret_cast<const float4*>(
                src + (size_t)(row0 + r) * DIM + dc * DC + c4 * 4);
            if (MODE == 1) {
                const float4 zv = *reinterpret_cast<const float4*>(
                    emb + (size_t)idxs[r] * DIM + dc * DC + c4 * 4);
                sv.x -= zv.x; sv.y -= zv.y; sv.z -= zv.z; sv.w -= zv.w;
            }
            float* dr = &rs[r][c4 * 4];
            reinterpret_cast<float2*>(dr)[0] = make_float2(sv.x, sv.y);
            reinterpret_cast<float2*>(dr)[1] = make_float2(sv.z, sv.w);
            const int dl = r;
            const float4 wv = *reinterpret_cast<const float4*>(
                W + (size_t)(dc * DC + dl) * DIM + e0 + c4 * 4);
            wsl[c4 * 4 + 0][dl] = wv.x;
            wsl[c4 * 4 + 1][dl] = wv.y;
            wsl[c4 * 4 + 2][dl] = wv.z;
            wsl[c4 * 4 + 3][dl] = wv.w;
        }
        __syncthreads();
#pragma unroll
        for (int d2 = 0; d2 < DC / 2; ++d2) {
            float2 xr[4], wk[4];
#pragma unroll
            for (int jj = 0; jj < 4; ++jj) {
                xr[jj] = reinterpret_cast<const float2*>(&rs[ty + 16 * jj][0])[d2];
                wk[jj] = reinterpret_cast<const float2*>(&wsl[tx + 16 * jj][0])[d2];
            }
#pragma unroll
            for (int a = 0; a < 4; ++a)
#pragma unroll
                for (int b = 0; b < 4; ++b)
                    acc[a][b] += xr[a].x * wk[b].x + xr[a].y * wk[b].y;
        }
    }

#pragma unroll
    for (int a = 0; a < 4; ++a)
#pragma unroll
        for (int b = 0; b < 4; ++b) {
            const int row_l = ty + 16 * a;
            const int e = e0 + tx + 16 * b;
            float v = acc[a][b] + bias[e];
            if (MODE == 1) {
                v = fmaxf(v, 0.f);
            } else {
                v += emb[(size_t)idxs[row_l] * DIM + e];
            }
            out[(size_t)(row0 + row_l) * DIM + e] = v;
        }
}

// ---------------- loss: BETA * mean(exact min dist) ----------------
__global__ void loss_kernel(const float* __restrict__ minq, float* __restrict__ loss_out) {
    const int tid = threadIdx.x;
    float s = 0.f;
    for (int i = tid; i < N_TOK; i += 256) s += minq[i];
#pragma unroll
    for (int o = 32; o > 0; o >>= 1) s += __shfl_down(s, o, 64);
    __shared__ float sb[4];
    if ((tid & 63) == 0) sb[tid >> 6] = s;
    __syncthreads();
    if (tid == 0) loss_out[0] = BETA_C * ((sb[0] + sb[1] + sb[2] + sb[3]) / (float)N_TOK);
}

extern "C" void kernel_launch(void* const* d_in, const int* in_sizes, int n_in,
                              void* d_out, int out_size, void* d_ws, size_t ws_size,
                              hipStream_t stream) {
    const float* x   = (const float*)d_in[0];
    const float* emb = (const float*)d_in[1];
    const float* W1  = (const float*)d_in[2];
    const float* b1  = (const float*)d_in[3];
    const float* W2  = (const float*)d_in[4];
    const float* b2  = (const float*)d_in[5];

    float* z_out = (float*)d_out;
    float* loss_out = z_out + (size_t)N_TOK * DIM;

    // workspace — exactly 17,039,360 B (the R1/R2-proven footprint):
    //   [0,32K)                 enorm
    //   [32K,96K)               idx
    //   [96K,160K)              minq
    //   [256K, +4M)             eh plane        \
    //   [+4M, +8M)              el plane         | dist-phase lifetime;
    //   [+8M, +10M)             xh slab plane    | all aliased by h (16 MB)
    //   [+10M, +12M)            xl slab plane    | during the MLP phase
    //   [+12M, +16M)            merge buf       /
    char* ws = (char*)d_ws;
    float*    enorm = (float*)(ws);
    int*      idxb  = (int*)(ws + 32768);
    float*    minq  = (float*)(ws + 98304);
    ushort_t* eh    = (ushort_t*)(ws + 262144);
    ushort_t* el    = (ushort_t*)(ws + 4456448);
    ushort_t* xh_s  = (ushort_t*)(ws + 8650752);
    ushort_t* xl_s  = (ushort_t*)(ws + 10747904);
    uint4*    mg    = (uint4*)(ws + 12845056);
    float*    h     = (float*)(ws + 262144);     // aliases planes+merge (disjoint lifetime)

    hipLaunchKernelGGL((prep_kernel<1>), dim3(KCB / 4), dim3(256), 0, stream,
                       emb, eh, el, enorm, KCB);
    for (int s = 0; s < NSLAB; ++s) {
        hipLaunchKernelGGL((prep_kernel<0>), dim3(SLAB / 4), dim3(256), 0, stream,
                           x + (size_t)s * SLAB * DIM, xh_s, xl_s, (float*)nullptr, SLAB);
        hipLaunchKernelGGL(dist_kernel, dim3(SLAB / 128, NSTRIPE), dim3(256), 0, stream,
                           xh_s, xl_s, eh, el, enorm, mg);
        hipLaunchKernelGGL(merge_fixup_kernel, dim3(SLAB / 4), dim3(256), 0, stream,
                           x, emb, mg, idxb, minq, s * SLAB);
    }
    hipLaunchKernelGGL((mlp_kernel<1>), dim3(N_TOK / BR, DIM / BKT), dim3(256), 0, stream,
                       x, emb, idxb, W1, b1, h);
    hipLaunchKernelGGL((mlp_kernel<2>), dim3(N_TOK / BR, DIM / BKT), dim3(256), 0, stream,
                       h, emb, idxb, W2, b2, z_out);
    hipLaunchKernelGGL(loss_kernel, dim3(1), dim3(256), 0, stream, minq, loss_out);
}

// Round 4
// 415.286 us; speedup vs baseline: 1.5501x; 1.5501x over previous
//
#include <hip/hip_runtime.h>
#include <cfloat>

// Problem constants (B=8, S=2048, D=256, K=8192)
#define N_TOK 16384
#define DIM 256
#define KCB 8192
#define BETA_C 0.25f
#define SLAB 4096
#define NSLAB 4
#define NSPLIT 16          // col splits per slab-launch; 512 cols each
#define KT_PER 4           // k-tiles of 128 cols per block
#define NCHUNK 48          // KT_PER * 12 chunk-pairs (3 passes x 4 d-chunks)

typedef __attribute__((ext_vector_type(8))) short short8;   // 8 bf16 (4 VGPRs)
typedef __attribute__((ext_vector_type(4))) float f32x4;    // MFMA acc
typedef unsigned short ushort_t;

// Swizzled byte offset within a [rows][ROWB bytes] LDS tile.
// XOR of byte-bits 4-6 with row&7: conflict-free b128 frag reads (proven R2/R3).
__device__ __forceinline__ int swzb(int byte_in_row) { return byte_in_row; } // doc only

__device__ __forceinline__ void async_copy16(const void* g, void* l) {
    __builtin_amdgcn_global_load_lds(
        (const __attribute__((address_space(1))) unsigned int*)g,
        (__attribute__((address_space(3))) unsigned int*)l, 16, 0, 0);
}

// ---------------- prep: f32 row -> packed bf16 [hi(256) | lo(256)] (+ norm) -------
template <int WITH_NORM>
__global__ void __launch_bounds__(256)
prep2_kernel(const float* __restrict__ src, ushort_t* __restrict__ dst,
             float* __restrict__ norm, int nrows) {
    const int w = threadIdx.x >> 6, lane = threadIdx.x & 63;
    const int r = blockIdx.x * 4 + w;
    if (r >= nrows) return;
    const float4 v = *reinterpret_cast<const float4*>(src + (size_t)r * DIM + lane * 4);
    const float vv[4] = {v.x, v.y, v.z, v.w};
    unsigned hw[2], lw[2];
    float s = 0.f;
#pragma unroll
    for (int j = 0; j < 2; ++j) {
        unsigned h0, h1, l0, l1;
        {
            const float f = vv[2 * j];
            s += f * f;
            const unsigned u = __float_as_uint(f);
            h0 = u >> 16;
            l0 = __float_as_uint(f - __uint_as_float(u & 0xFFFF0000u)) >> 16;
        }
        {
            const float f = vv[2 * j + 1];
            s += f * f;
            const unsigned u = __float_as_uint(f);
            h1 = u >> 16;
            l1 = __float_as_uint(f - __uint_as_float(u & 0xFFFF0000u)) >> 16;
        }
        hw[j] = h0 | (h1 << 16);
        lw[j] = l0 | (l1 << 16);
    }
    ushort_t* row = dst + (size_t)r * 512;
    *reinterpret_cast<uint2*>(row + lane * 4) = make_uint2(hw[0], hw[1]);
    *reinterpret_cast<uint2*>(row + 256 + lane * 4) = make_uint2(lw[0], lw[1]);
    if (WITH_NORM) {
#pragma unroll
        for (int o = 32; o > 0; o >>= 1) s += __shfl_down(s, o, 64);
        if (lane == 0) norm[r] = s;
    }
}

// ---------------- W transpose to bf16: WT[e][d] = bf16(W[d][e]) ----------------
__global__ void wt_kernel(const float* __restrict__ W, ushort_t* __restrict__ WT) {
    const int flat = blockIdx.x * 256 + threadIdx.x;   // 65536 elems, grid 256
    const int d = flat >> 8, e = flat & 255;
    WT[(size_t)e * 256 + d] = (ushort_t)(__float_as_uint(W[flat]) >> 16);
}

// ---------------- MFMA distance GEMM (virtual K=768) + top-2 per split ----------
// Block: 128 slab rows x 512 cols (4 k-tiles of 128). Double-buffered chunks.
__global__ void __launch_bounds__(256, 2)
dist_kernel(const ushort_t* __restrict__ X2, const ushort_t* __restrict__ E2,
            const float* __restrict__ enorm, uint4* __restrict__ mg) {
    __shared__ char sb[65536];   // A bufs @0,16K; B bufs @32K,48K; epilogue sc = all

    const int tid = threadIdx.x;
    const int lane = tid & 63;
    const int w = tid >> 6;
    const int wy = w >> 1, wx = w & 1;
    const int l15 = lane & 15, l4 = lane >> 4;
    const int row0 = blockIdx.x * 128;          // slab-local
    const int col_base = blockIdx.y * 512;      // global code col
    const int rr = lane >> 3;
    const int egr = (lane & 7) ^ rr;            // pre-swizzled source granule

    float tv1[16], tv2[16];
    int ti1[16], ti2[16];
#pragma unroll
    for (int s = 0; s < 16; ++s) { tv1[s] = FLT_MAX; tv2[s] = FLT_MAX; ti1[s] = 0; ti2[s] = 0; }

    f32x4 acc[4][4];

    // chunk descriptor: c -> (kt, pass p, d-quarter dq)
    //   aoff = (p==1?256:0)+dq*64 ; boff = (p==2?256:0)+dq*64 (ushort offsets)
#define STAGE_CHUNK(buf, c)                                                        \
    {                                                                              \
        const int kt_ = (c) / 12, cp_ = (c) % 12;                                  \
        const int p_ = cp_ >> 2, dq_ = cp_ & 3;                                    \
        const int aoff_ = ((p_ == 1) ? 256 : 0) + dq_ * 64;                        \
        const int boff_ = ((p_ == 2) ? 256 : 0) + dq_ * 64;                        \
        const ushort_t* Ab_ = X2 + (size_t)row0 * 512 + aoff_ + egr * 8;           \
        const ushort_t* Bb_ = E2 + (size_t)(col_base + kt_ * 128) * 512 + boff_ + egr * 8; \
        char* Al_ = sb + (buf) * 16384;                                            \
        char* Bl_ = sb + 32768 + (buf) * 16384;                                    \
        _Pragma("unroll")                                                          \
        for (int i_ = 0; i_ < 4; ++i_) {                                           \
            const int g_ = w * 4 + i_;                                             \
            async_copy16(Ab_ + (size_t)(g_ * 8 + rr) * 512, Al_ + g_ * 1024);      \
            async_copy16(Bb_ + (size_t)(g_ * 8 + rr) * 512, Bl_ + g_ * 1024);      \
        }                                                                          \
    }

    STAGE_CHUNK(0, 0)
    __syncthreads();   // drains vmcnt(0): buf0 ready

    for (int c = 0; c < NCHUNK; ++c) {
        const int cur = c & 1;
        const int cp = c % 12;
        if (c + 1 < NCHUNK) STAGE_CHUNK(cur ^ 1, c + 1)

        if (cp == 0) {
#pragma unroll
            for (int m = 0; m < 4; ++m)
#pragma unroll
                for (int n = 0; n < 4; ++n) {
                    f32x4 z = {0.f, 0.f, 0.f, 0.f};
                    acc[m][n] = z;
                }
        }

        const char* Al = sb + cur * 16384;
        const char* Bl = sb + 32768 + cur * 16384;
#pragma unroll
        for (int ks = 0; ks < 2; ++ks) {
            short8 af[4], bf[4];
#pragma unroll
            for (int m = 0; m < 4; ++m) {
                const int r = wy * 64 + m * 16 + l15;
                af[m] = *reinterpret_cast<const short8*>(
                    Al + r * 128 + ((ks * 64 + l4 * 16) ^ ((r & 7) << 4)));
            }
#pragma unroll
            for (int n = 0; n < 4; ++n) {
                const int r = wx * 64 + n * 16 + l15;
                bf[n] = *reinterpret_cast<const short8*>(
                    Bl + r * 128 + ((ks * 64 + l4 * 16) ^ ((r & 7) << 4)));
            }
#pragma unroll
            for (int m = 0; m < 4; ++m)
#pragma unroll
                for (int n = 0; n < 4; ++n)
                    acc[m][n] = __builtin_amdgcn_mfma_f32_16x16x32_bf16(af[m], bf[n], acc[m][n], 0, 0, 0);
        }

        if (cp == 11) {   // k-tile complete: dist = enorm - 2*dot; top-2 update
            const int k0 = col_base + (c / 12) * 128;
#pragma unroll
            for (int n = 0; n < 4; ++n) {
                const int kg = k0 + wx * 64 + n * 16 + l15;
                const float en = enorm[kg];
#pragma unroll
                for (int m = 0; m < 4; ++m)
#pragma unroll
                    for (int j = 0; j < 4; ++j) {
                        const float v = fmaf(-2.f, acc[m][n][j], en);
                        const int s = m * 4 + j;
                        if (v < tv1[s]) {
                            tv2[s] = tv1[s]; ti2[s] = ti1[s];
                            tv1[s] = v; ti1[s] = kg;
                        } else if (v < tv2[s]) {
                            tv2[s] = v; ti2[s] = kg;
                        }
                    }
            }
        }
        __syncthreads();   // next buf staged; all readers of cur done
    }

    // block-level merge: 32 contributors per row -> top-2 (conflict-free layout)
    uint4* sc = reinterpret_cast<uint4*>(sb);   // sc[thr + 256*s]
#pragma unroll
    for (int s = 0; s < 16; ++s)
        sc[tid + 256 * s] = make_uint4(__float_as_uint(tv1[s]), (unsigned)ti1[s],
                                       __float_as_uint(tv2[s]), (unsigned)ti2[s]);
    __syncthreads();
    if (tid < 128) {
        const int r = tid;
        const int wy2 = r >> 6, lr = r & 63;
        const int m = lr >> 4, g = (lr & 15) >> 2, j = lr & 3, s = m * 4 + j;
        float v1 = FLT_MAX, v2 = FLT_MAX;
        int i1 = 0, i2 = 0;
        for (int wx2 = 0; wx2 < 2; ++wx2)
            for (int c = 0; c < 16; ++c) {
                const int thr = (wy2 * 2 + wx2) * 64 + g * 16 + c;
                const uint4 q = sc[thr + 256 * s];
                const float a1 = __uint_as_float(q.x), a2 = __uint_as_float(q.z);
                if (a1 < v1) {
                    if (a2 < v1) { v1 = a1; i1 = (int)q.y; v2 = a2; i2 = (int)q.w; }
                    else { v2 = v1; i2 = i1; v1 = a1; i1 = (int)q.y; }
                } else if (a1 < v2) { v2 = a1; i2 = (int)q.y; }
            }
        mg[(size_t)(row0 + r) * NSPLIT + blockIdx.y] =
            make_uint4(__float_as_uint(v1), (unsigned)i1, __float_as_uint(v2), (unsigned)i2);
    }
}

// ---------------- merge splits + exact f32 rescore ----------------
__global__ void __launch_bounds__(256)
merge_fixup_kernel(const float* __restrict__ x, const float* __restrict__ emb,
                   const uint4* __restrict__ mg, int* __restrict__ idx_out,
                   float* __restrict__ minq, int row_base) {
    const int w = threadIdx.x >> 6, lane = threadIdx.x & 63;
    const int nl = blockIdx.x * 4 + w;
    const int n = row_base + nl;
    const uint4 q = mg[(size_t)nl * NSPLIT + (lane & 15)];
    float v1 = __uint_as_float(q.x), v2 = __uint_as_float(q.z);
    int i1 = (int)q.y, i2 = (int)q.w;
#pragma unroll
    for (int o = 1; o < 16; o <<= 1) {
        const float b1 = __shfl_xor(v1, o, 64), b2 = __shfl_xor(v2, o, 64);
        const int j1 = __shfl_xor(i1, o, 64), j2 = __shfl_xor(i2, o, 64);
        const bool bf_ = (b1 < v1) || (b1 == v1 && j1 < i1);
        const float nv1 = bf_ ? b1 : v1; const int ni1 = bf_ ? j1 : i1;
        const float c = bf_ ? v1 : b1;   const int ci = bf_ ? i1 : j1;
        const float d = bf_ ? b2 : v2;   const int di = bf_ ? j2 : i2;
        const bool ds_ = (d < c) || (d == c && di < ci);
        v1 = nv1; i1 = ni1;
        v2 = ds_ ? d : c; i2 = ds_ ? di : ci;
    }
    const float4 xv = *reinterpret_cast<const float4*>(x + (size_t)n * DIM + lane * 4);
    float dsum[2];
    const int cand[2] = {i1, i2};
#pragma unroll
    for (int c = 0; c < 2; ++c) {
        const float4 ev = *reinterpret_cast<const float4*>(emb + (size_t)cand[c] * DIM + lane * 4);
        const float dx = xv.x - ev.x, dy = xv.y - ev.y, dz = xv.z - ev.z, dw = xv.w - ev.w;
        float s = dx * dx + dy * dy + dz * dz + dw * dw;
#pragma unroll
        for (int o = 32; o > 0; o >>= 1) s += __shfl_xor(s, o, 64);
        dsum[c] = s;
    }
    const bool take2 = (dsum[1] < dsum[0]) || (dsum[1] == dsum[0] && cand[1] < cand[0]);
    if (lane == 0) {
        idx_out[n] = take2 ? cand[1] : cand[0];
        minq[n] = take2 ? dsum[1] : dsum[0];
    }
}

// ---------------- fused MLP: z = e + W2^T-gemm(relu(W1^T-gemm(x-e)+b1))+b2 -------
// Block: 64 rows, 4 waves (each owns 64 out-cols). h lives only in LDS (bf16).
__global__ void __launch_bounds__(256)
fused_mlp_kernel(const float* __restrict__ x, const float* __restrict__ emb,
                 const int* __restrict__ idx, const ushort_t* __restrict__ W1T,
                 const ushort_t* __restrict__ W2T, const float* __restrict__ b1,
                 const float* __restrict__ b2, float* __restrict__ z) {
    __shared__ char sb[65536];   // [0,32K): A/h tile [64 rows][512B]; [32K,64K): W chunk [256][128B]
    __shared__ int idxs[64];

    const int tid = threadIdx.x;
    const int lane = tid & 63;
    const int w = tid >> 6;
    const int l15 = lane & 15, l4 = lane >> 4;
    const int rr = lane >> 3;
    const int egr = (lane & 7) ^ rr;
    const int row0 = blockIdx.x * 64;

    if (tid < 64) idxs[tid] = idx[row0 + tid];
    __syncthreads();

    // stage r = bf16(x - emb[idx]) into swizzled [64][256]-bf16 tile (512 B rows)
#pragma unroll
    for (int j = 0; j < 16; ++j) {
        const int flat = tid + 256 * j;       // 0..4095
        const int r = flat >> 6;              // 64 rows
        const int sg = flat & 63;             // 64 segs of 4 floats
        const float4 xv = *reinterpret_cast<const float4*>(x + (size_t)(row0 + r) * DIM + sg * 4);
        const float4 ev = *reinterpret_cast<const float4*>(emb + (size_t)idxs[r] * DIM + sg * 4);
        const unsigned u0 = __float_as_uint(xv.x - ev.x), u1 = __float_as_uint(xv.y - ev.y);
        const unsigned u2 = __float_as_uint(xv.z - ev.z), u3 = __float_as_uint(xv.w - ev.w);
        const uint2 pk = make_uint2((u0 >> 16) | (u1 & 0xFFFF0000u),
                                    (u2 >> 16) | (u3 & 0xFFFF0000u));
        *reinterpret_cast<uint2*>(sb + r * 512 + ((sg * 8) ^ ((r & 7) << 4))) = pk;
    }

    const ushort_t* Wp[2] = {W1T, W2T};
    f32x4 acc[4][4];

    for (int layer = 0; layer < 2; ++layer) {
        const ushort_t* WT = Wp[layer];
#pragma unroll
        for (int m = 0; m < 4; ++m)
#pragma unroll
            for (int n = 0; n < 4; ++n) {
                f32x4 zz = {0.f, 0.f, 0.f, 0.f};
                acc[m][n] = zz;
            }
        for (int kc = 0; kc < 4; ++kc) {
            __syncthreads();   // previous chunk's readers done (and A-tile writes on kc=0)
            // stage WT[:, kc*64..] as [256 out][64 k] bf16 tile (swizzled via source)
#pragma unroll
            for (int i = 0; i < 2; ++i) {
                const int g = w * 8 + i * 4 + (lane >> 4);   // not used; keep simple below
            }
#pragma unroll
            for (int i = 0; i < 8; ++i) {
                const int g = w * 8 + i;   // granule: 8 out-rows
                async_copy16(WT + (size_t)(g * 8 + rr) * 256 + kc * 64 + egr * 8,
                             sb + 32768 + g * 1024);
            }
            __syncthreads();   // vmcnt drained
#pragma unroll
            for (int ks = 0; ks < 2; ++ks) {
                short8 af[4], bf[4];
#pragma unroll
                for (int m = 0; m < 4; ++m) {
                    const int r = m * 16 + l15;
                    af[m] = *reinterpret_cast<const short8*>(
                        sb + r * 512 + ((((kc * 2 + ks) * 64) + l4 * 16) ^ ((r & 7) << 4)));
                }
#pragma unroll
                for (int n = 0; n < 4; ++n) {
                    const int r = w * 64 + n * 16 + l15;
                    bf[n] = *reinterpret_cast<const short8*>(
                        sb + 32768 + r * 128 + ((ks * 64 + l4 * 16) ^ ((r & 7) << 4)));
                }
#pragma unroll
                for (int m = 0; m < 4; ++m)
#pragma unroll
                    for (int n = 0; n < 4; ++n)
                        acc[m][n] = __builtin_amdgcn_mfma_f32_16x16x32_bf16(af[m], bf[n], acc[m][n], 0, 0, 0);
            }
        }

        if (layer == 0) {
            // h = relu(acc + b1) -> bf16 -> overwrite A-tile
            float b1v[4];
#pragma unroll
            for (int n = 0; n < 4; ++n) b1v[n] = b1[w * 64 + n * 16 + l15];
            __syncthreads();   // all GEMM1 A-tile reads done before overwrite
#pragma unroll
            for (int m = 0; m < 4; ++m)
#pragma unroll
                for (int n = 0; n < 4; ++n)
#pragma unroll
                    for (int j = 0; j < 4; ++j) {
                        const int row = m * 16 + l4 * 4 + j;
                        const int col = w * 64 + n * 16 + l15;
                        const float hv = fmaxf(acc[m][n][j] + b1v[n], 0.f);
                        *reinterpret_cast<ushort_t*>(
                            sb + row * 512 + ((col * 2) ^ ((row & 7) << 4))) =
                            (ushort_t)(__float_as_uint(hv) >> 16);
                    }
            __syncthreads();   // h-tile visible to all waves
        } else {
            // z = acc + b2 + emb[idx]
            float b2v[4];
#pragma unroll
            for (int n = 0; n < 4; ++n) b2v[n] = b2[w * 64 + n * 16 + l15];
#pragma unroll
            for (int m = 0; m < 4; ++m)
#pragma unroll
                for (int n = 0; n < 4; ++n)
#pragma unroll
                    for (int j = 0; j < 4; ++j) {
                        const int row = m * 16 + l4 * 4 + j;
                        const int col = w * 64 + n * 16 + l15;
                        const float ev = emb[(size_t)idxs[row] * DIM + col];
                        z[(size_t)(row0 + row) * DIM + col] = acc[m][n][j] + b2v[n] + ev;
                    }
        }
    }
}

// ---------------- loss: BETA * mean(exact min dist) ----------------
__global__ void loss_kernel(const float* __restrict__ minq, float* __restrict__ loss_out) {
    const int tid = threadIdx.x;
    float s = 0.f;
    for (int i = tid; i < N_TOK; i += 256) s += minq[i];
#pragma unroll
    for (int o = 32; o > 0; o >>= 1) s += __shfl_down(s, o, 64);
    __shared__ float sbf[4];
    if ((tid & 63) == 0) sbf[tid >> 6] = s;
    __syncthreads();
    if (tid == 0) loss_out[0] = BETA_C * ((sbf[0] + sbf[1] + sbf[2] + sbf[3]) / (float)N_TOK);
}

extern "C" void kernel_launch(void* const* d_in, const int* in_sizes, int n_in,
                              void* d_out, int out_size, void* d_ws, size_t ws_size,
                              hipStream_t stream) {
    const float* x   = (const float*)d_in[0];
    const float* emb = (const float*)d_in[1];
    const float* W1  = (const float*)d_in[2];
    const float* b1  = (const float*)d_in[3];
    const float* W2  = (const float*)d_in[4];
    const float* b2  = (const float*)d_in[5];

    float* z_out = (float*)d_out;
    float* loss_out = z_out + (size_t)N_TOK * DIM;

    // workspace (14.1 MB used, all disjoint; proven budget >= 17.0 MB):
    //   [0,32K)            enorm
    //   [32K,96K)          idx
    //   [96K,160K)         minq
    //   [160K,288K)        W1T bf16
    //   [288K,416K)        W2T bf16
    //   [448K, +8M)        E2  [8192][512] bf16 (eh|el)
    //   [+8M, +4M)         X2  [4096][512] bf16 slab (xh|xl)
    //   [..., +1M)         mg  [4096][16] uint4
    char* ws = (char*)d_ws;
    float*    enorm = (float*)(ws);
    int*      idxb  = (int*)(ws + 32768);
    float*    minq  = (float*)(ws + 98304);
    ushort_t* W1T   = (ushort_t*)(ws + 163840);
    ushort_t* W2T   = (ushort_t*)(ws + 294912);
    ushort_t* E2    = (ushort_t*)(ws + 458752);
    ushort_t* X2    = (ushort_t*)(ws + 8847360);
    uint4*    mg    = (uint4*)(ws + 13041664);

    hipLaunchKernelGGL((prep2_kernel<1>), dim3(KCB / 4), dim3(256), 0, stream,
                       emb, E2, enorm, KCB);
    hipLaunchKernelGGL(wt_kernel, dim3(256), dim3(256), 0, stream, W1, W1T);
    hipLaunchKernelGGL(wt_kernel, dim3(256), dim3(256), 0, stream, W2, W2T);
    for (int s = 0; s < NSLAB; ++s) {
        hipLaunchKernelGGL((prep2_kernel<0>), dim3(SLAB / 4), dim3(256), 0, stream,
                           x + (size_t)s * SLAB * DIM, X2, (float*)nullptr, SLAB);
        hipLaunchKernelGGL(dist_kernel, dim3(SLAB / 128, NSPLIT), dim3(256), 0, stream,
                           X2, E2, enorm, mg);
        hipLaunchKernelGGL(merge_fixup_kernel, dim3(SLAB / 4), dim3(256), 0, stream,
                           x, emb, mg, idxb, minq, s * SLAB);
    }
    hipLaunchKernelGGL(fused_mlp_kernel, dim3(N_TOK / 64), dim3(256), 0, stream,
                       x, emb, idxb, W1T, W2T, b1, b2, z_out);
    hipLaunchKernelGGL(loss_kernel, dim3(1), dim3(256), 0, stream, minq, loss_out);
}